// Round 1
// baseline (451.680 us; speedup 1.0000x reference)
//
#include <hip/hip_runtime.h>

// GAT layer, N=8192, F_IN=256, F_OUT=128.
// K1 wh: Wh = h@W (fp32 VALU) + WhT (f16 transposed [c][j]).  512 blocks.
// K2 f12: f1 = Wh@a1, f2 = Wh@a2.
// K3 attn: barrier-free streaming. adj has ZERO reuse -> read it straight from
//   HBM as per-thread int4 (quad pairs tile full 64B lines, 100% utilization);
//   no LDS staging, no DMA, no in-loop waitcnt/barrier. f2 (x32 reuse) staged
//   once in LDS. adj loads issued before B-frags so bfr stays in the vmcnt
//   FIFO during score VALU. scores->f16->MFMA 16x16x32, psum via ones-MFMA.
// K4 comb: (part0+part1)/(s0+s1).

#define N_NODES 8192
#define F_IN 256
#define F_OUT 128
#define RPB 32                      // rows per block
#define JCH 128                     // j per chunk (per iteration)
#define JSPLIT 2
#define JRANGE (N_NODES / JSPLIT)   // 4096
#define NCH (JRANGE / JCH)          // 32 iterations

typedef _Float16 half8 __attribute__((ext_vector_type(8)));
typedef float floatx4 __attribute__((ext_vector_type(4)));
typedef float f32x4 __attribute__((ext_vector_type(4)));

__device__ __align__(16) float g_Wh[N_NODES * F_OUT];                  // 4 MB
__device__ __align__(16) _Float16 g_WhT[(size_t)F_OUT * N_NODES];      // 2 MB
__device__ __align__(16) float g_f1[N_NODES];
__device__ __align__(16) float g_f2[N_NODES];
__device__ __align__(16) float g_part[JSPLIT][N_NODES * F_OUT];        // 8 MB
__device__ __align__(16) float g_spart[JSPLIT][N_NODES];               // 64 KB

// ---------------- Kernel A: Wh = h @ W ----------------
__global__ __launch_bounds__(256, 2) void wh_kernel(
    const float* __restrict__ h, const float* __restrict__ W) {
  __shared__ float hT[F_IN][20];  // pad 20 keeps &hT[k][rg*8] 16B-aligned
  const int t = threadIdx.x;
  const int i0 = blockIdx.x * 16;
  {
    const int row = t >> 4;   // 0..15
    const int fu = t & 15;    // float4 unit
#pragma unroll
    for (int r = 0; r < 4; ++r) {
      const int ku = r * 16 + fu;  // 0..63
      const float4 v = *(const float4*)(h + (size_t)(i0 + row) * F_IN + ku * 4);
      hT[ku * 4 + 0][row] = v.x; hT[ku * 4 + 1][row] = v.y;
      hT[ku * 4 + 2][row] = v.z; hT[ku * 4 + 3][row] = v.w;
    }
  }
  __syncthreads();
  const int c = t & 127;
  const int rg = t >> 7;   // 8 rows per thread
  float acc[8];
#pragma unroll
  for (int r = 0; r < 8; ++r) acc[r] = 0.f;
#pragma unroll 8
  for (int k = 0; k < F_IN; ++k) {
    const float wv = W[k * F_OUT + c];
    const float4 x0 = *(const float4*)(&hT[k][rg * 8]);      // lane-uniform -> broadcast
    const float4 x1 = *(const float4*)(&hT[k][rg * 8 + 4]);
    acc[0] = fmaf(x0.x, wv, acc[0]); acc[1] = fmaf(x0.y, wv, acc[1]);
    acc[2] = fmaf(x0.z, wv, acc[2]); acc[3] = fmaf(x0.w, wv, acc[3]);
    acc[4] = fmaf(x1.x, wv, acc[4]); acc[5] = fmaf(x1.y, wv, acc[5]);
    acc[6] = fmaf(x1.z, wv, acc[6]); acc[7] = fmaf(x1.w, wv, acc[7]);
  }
#pragma unroll
  for (int r = 0; r < 8; ++r)
    g_Wh[(size_t)(i0 + rg * 8 + r) * F_OUT + c] = acc[r];
  union { _Float16 hh[8]; uint4 u4; } pk;
#pragma unroll
  for (int r = 0; r < 8; ++r) pk.hh[r] = (_Float16)acc[r];
  *(uint4*)(g_WhT + (size_t)c * N_NODES + i0 + rg * 8) = pk.u4;
}

// ---------------- Kernel B: f1 = Wh@a1, f2 = Wh@a2 ----------------
__global__ __launch_bounds__(256) void f12_kernel(const float* __restrict__ a) {
  const int t = threadIdx.x;
  const int row = blockIdx.x * 2 + (t >> 7);
  const int c = t & 127;
  const float wh = g_Wh[(size_t)row * F_OUT + c];
  float p1 = wh * a[c];
  float p2 = wh * a[F_OUT + c];
  for (int o = 32; o > 0; o >>= 1) {
    p1 += __shfl_down(p1, o, 64);
    p2 += __shfl_down(p2, o, 64);
  }
  __shared__ float s1[4], s2[4];
  const int w = t >> 6;
  if ((t & 63) == 0) { s1[w] = p1; s2[w] = p2; }
  __syncthreads();
  if ((t & 127) == 0) {
    g_f1[row] = s1[w] + s1[w + 1];
    g_f2[row] = s2[w] + s2[w + 1];
  }
}

// ---------------- Kernel C: fused attention (partials) ----------------
__device__ __forceinline__ float score_p(int a, float f2v, float f1r) {
  float s = f1r + f2v;
  s = fmaxf(s, 0.2f * s);  // leaky_relu, alpha=0.2<1
  float arg = (a > 0) ? fmaf(s, 1.44269504088896f, -16.0f) : -1.0e5f;
  return __builtin_amdgcn_exp2f(arg);  // masked -> 0; 2^-16 scale cancels in num/den
}

__global__ __launch_bounds__(256, 2) void gat_attn_kernel(const int* __restrict__ adj) {
  const int t = threadIdx.x;
  const int wave = t >> 6;
  const int lane = t & 63;
  const int mrow = lane & 15;
  const int quad = lane >> 4;
  const int i0 = blockIdx.x * RPB;
  const int js = blockIdx.y;
  const int jbase = js * JRANGE;

  __shared__ float ldsF2[JRANGE];        // 16 KB, whole j-half of f2
  __shared__ float ldsO[RPB][F_OUT];     // 16 KB
  __shared__ float ldsS[4][RPB];

  // runtime C/D layout probe: D1[m][n]=m, D2[m][n]=n (self-correcting scatter)
  int rm[4], cm[4];
  {
    half8 a1f, b1f, a2f, b2f;
#pragma unroll
    for (int e = 0; e < 8; ++e) {
      a1f[e] = (_Float16)0; b1f[e] = (_Float16)0;
      a2f[e] = (_Float16)0; b2f[e] = (_Float16)0;
    }
    if (quad == 0) {
      a1f[0] = (_Float16)mrow; b1f[0] = (_Float16)1;
      a2f[0] = (_Float16)1;    b2f[0] = (_Float16)mrow;
    }
    floatx4 d1 = (floatx4)0.f, d2 = (floatx4)0.f;
    d1 = __builtin_amdgcn_mfma_f32_16x16x32_f16(a1f, b1f, d1, 0, 0, 0);
    d2 = __builtin_amdgcn_mfma_f32_16x16x32_f16(a2f, b2f, d2, 0, 0, 0);
#pragma unroll
    for (int r = 0; r < 4; ++r) { rm[r] = (int)d1[r]; cm[r] = (int)d2[r]; }
  }

  const float f1r0 = g_f1[i0 + mrow];
  const float f1r1 = g_f1[i0 + 16 + mrow];

  half8 ones;
#pragma unroll
  for (int e = 0; e < 8; ++e) ones[e] = (_Float16)1;

  floatx4 acc[2][8];
  floatx4 asum[2];
#pragma unroll
  for (int tl = 0; tl < 2; ++tl) {
    asum[tl] = (floatx4)0.f;
#pragma unroll
    for (int ct = 0; ct < 8; ++ct) acc[tl][ct] = (floatx4)0.f;
  }

  // stage the f2 half once (x32-row reuse justifies LDS; adj has none)
#pragma unroll
  for (int it = 0; it < 4; ++it) {
    const int u = it * 256 + t;
    *(float4*)&ldsF2[u * 4] = *(const float4*)(g_f2 + jbase + u * 4);
  }
  __syncthreads();

  const size_t rowoff0 = (size_t)(i0 + mrow) * N_NODES;
  const size_t rowoff1 = (size_t)(i0 + 16 + mrow) * N_NODES;
  const int jloc = wave * 32 + quad * 8;

#pragma unroll 1
  for (int c = 0; c < NCH; ++c) {
    const int jglob = jbase + c * JCH + jloc;

    // adj straight from HBM: 4 x int4 per thread. quads 0,1 and 2,3 tile full
    // 64B lines -> 100% line utilization. Issued FIRST so the bfr loads below
    // stay outstanding in the vmcnt FIFO while the score VALU runs.
    const int4 A00 = *(const int4*)(adj + rowoff0 + jglob);
    const int4 A01 = *(const int4*)(adj + rowoff0 + jglob + 4);
    const int4 A10 = *(const int4*)(adj + rowoff1 + jglob);
    const int4 A11 = *(const int4*)(adj + rowoff1 + jglob + 4);

    // B-frags from L2/L3 direct to VGPR
    half8 bfr[8];
#pragma unroll
    for (int ct = 0; ct < 8; ++ct)
      bfr[ct] = *(const half8*)(g_WhT + (size_t)(ct * 16 + mrow) * N_NODES + jglob);

    const float4 F0 = *(const float4*)&ldsF2[c * JCH + jloc];
    const float4 F1 = *(const float4*)&ldsF2[c * JCH + jloc + 4];

    half8 af0, af1;
    af0[0] = (_Float16)score_p(A00.x, F0.x, f1r0);
    af0[1] = (_Float16)score_p(A00.y, F0.y, f1r0);
    af0[2] = (_Float16)score_p(A00.z, F0.z, f1r0);
    af0[3] = (_Float16)score_p(A00.w, F0.w, f1r0);
    af0[4] = (_Float16)score_p(A01.x, F1.x, f1r0);
    af0[5] = (_Float16)score_p(A01.y, F1.y, f1r0);
    af0[6] = (_Float16)score_p(A01.z, F1.z, f1r0);
    af0[7] = (_Float16)score_p(A01.w, F1.w, f1r0);
    af1[0] = (_Float16)score_p(A10.x, F0.x, f1r1);
    af1[1] = (_Float16)score_p(A10.y, F0.y, f1r1);
    af1[2] = (_Float16)score_p(A10.z, F0.z, f1r1);
    af1[3] = (_Float16)score_p(A10.w, F0.w, f1r1);
    af1[4] = (_Float16)score_p(A11.x, F1.x, f1r1);
    af1[5] = (_Float16)score_p(A11.y, F1.y, f1r1);
    af1[6] = (_Float16)score_p(A11.z, F1.z, f1r1);
    af1[7] = (_Float16)score_p(A11.w, F1.w, f1r1);

#pragma unroll
    for (int ct = 0; ct < 8; ++ct) {
      acc[0][ct] = __builtin_amdgcn_mfma_f32_16x16x32_f16(af0, bfr[ct], acc[0][ct], 0, 0, 0);
      acc[1][ct] = __builtin_amdgcn_mfma_f32_16x16x32_f16(af1, bfr[ct], acc[1][ct], 0, 0, 0);
    }
    asum[0] = __builtin_amdgcn_mfma_f32_16x16x32_f16(af0, ones, asum[0], 0, 0, 0);
    asum[1] = __builtin_amdgcn_mfma_f32_16x16x32_f16(af1, ones, asum[1], 0, 0, 0);
    // no barrier, no waitcnt: waves free-run, latency self-hidden
  }

  // psum per row (all cols of asum equal; take the 4 probed rows per quad)
  if (mrow == 0) {
#pragma unroll
    for (int tl = 0; tl < 2; ++tl)
#pragma unroll
      for (int r = 0; r < 4; ++r)
        ldsS[wave][tl * 16 + rm[r]] = asum[tl][r];
  }
  // serialized wave-add of the 32x128 tile
  for (int w = 0; w < 4; ++w) {
    if (wave == w) {
#pragma unroll
      for (int tl = 0; tl < 2; ++tl)
#pragma unroll
        for (int ct = 0; ct < 8; ++ct)
#pragma unroll
          for (int r = 0; r < 4; ++r) {
            float* p = &ldsO[tl * 16 + rm[r]][ct * 16 + cm[r]];
            if (w == 0) *p = acc[tl][ct][r];
            else        *p += acc[tl][ct][r];
          }
    }
    __syncthreads();
  }
  {
    const int row = t >> 3;
    const int c0 = (t & 7) * 16;
    float* dst = g_part[js] + (size_t)(i0 + row) * F_OUT + c0;
#pragma unroll
    for (int q = 0; q < 4; ++q)
      *(f32x4*)(dst + q * 4) = *(const f32x4*)(&ldsO[row][c0 + q * 4]);
    if (t < RPB)
      g_spart[js][i0 + t] = ldsS[0][t] + ldsS[1][t] + ldsS[2][t] + ldsS[3][t];
  }
}

// ---------------- Kernel D: combine partials + normalize ----------------
__global__ __launch_bounds__(256) void comb_kernel(float* __restrict__ out) {
  const int u = blockIdx.x * 256 + threadIdx.x;  // float4 unit
  const int row = u >> 5;                        // 32 float4 per row
  const float s = g_spart[0][row] + g_spart[1][row];
  const f32x4 v = ((const f32x4*)g_part[0])[u] + ((const f32x4*)g_part[1])[u];
  ((f32x4*)out)[u] = v * (1.0f / s);
}

extern "C" void kernel_launch(void* const* d_in, const int* in_sizes, int n_in,
                              void* d_out, int out_size, void* d_ws, size_t ws_size,
                              hipStream_t stream) {
  const float* h = (const float*)d_in[0];
  const int* adj = (const int*)d_in[1];
  const float* W = (const float*)d_in[2];
  const float* a = (const float*)d_in[3];
  float* out = (float*)d_out;
  (void)d_ws; (void)ws_size;

  wh_kernel<<<dim3(N_NODES / 16), dim3(256), 0, stream>>>(h, W);
  f12_kernel<<<dim3(N_NODES / 2), dim3(256), 0, stream>>>(a);
  gat_attn_kernel<<<dim3(N_NODES / RPB, JSPLIT), dim3(256), 0, stream>>>(adj);
  comb_kernel<<<dim3(N_NODES * F_OUT / 4 / 256), dim3(256), 0, stream>>>(out);
}

// Round 2
// 444.346 us; speedup vs baseline: 1.0165x; 1.0165x over previous
//
#include <hip/hip_runtime.h>

// GAT layer, N=8192, F_IN=256, F_OUT=128.
// K1 wh: Wh = h@W (fp32 VALU) + WhT (f16 transposed [c][j]).  512 blocks.
// K2 f12: f1 = Wh@a1, f2 = Wh@a2.
// K3 attn: latency-hiding rewrite. JSPLIT=4 -> 1024 blocks = 4 blocks/CU
//   (16 waves/CU). adj read straight from HBM as per-thread int4 with
//   REGISTER PREFETCH depth-1: iteration c issues bfr(c) then adj(c+1);
//   MFMA waits vmcnt(4) so the adj prefetch stays in flight across the
//   back-edge. Scores never wait on memory. f2 (x32 reuse) staged once in
//   LDS. No in-loop barriers.
// K4 comb: sum 4 partials / sum 4 spart.

#define N_NODES 8192
#define F_IN 256
#define F_OUT 128
#define RPB 32                      // rows per block
#define JCH 128                     // j per chunk (per iteration)
#define JSPLIT 4
#define JRANGE (N_NODES / JSPLIT)   // 2048
#define NCH (JRANGE / JCH)          // 16 iterations

typedef _Float16 half8 __attribute__((ext_vector_type(8)));
typedef float floatx4 __attribute__((ext_vector_type(4)));
typedef float f32x4 __attribute__((ext_vector_type(4)));

__device__ __align__(16) float g_Wh[N_NODES * F_OUT];                  // 4 MB
__device__ __align__(16) _Float16 g_WhT[(size_t)F_OUT * N_NODES];      // 2 MB
__device__ __align__(16) float g_f1[N_NODES];
__device__ __align__(16) float g_f2[N_NODES];
__device__ __align__(16) float g_part[JSPLIT][N_NODES * F_OUT];        // 16 MB
__device__ __align__(16) float g_spart[JSPLIT][N_NODES];               // 128 KB

// ---------------- Kernel A: Wh = h @ W ----------------
__global__ __launch_bounds__(256, 2) void wh_kernel(
    const float* __restrict__ h, const float* __restrict__ W) {
  __shared__ float hT[F_IN][20];  // pad 20 keeps &hT[k][rg*8] 16B-aligned
  const int t = threadIdx.x;
  const int i0 = blockIdx.x * 16;
  {
    const int row = t >> 4;   // 0..15
    const int fu = t & 15;    // float4 unit
#pragma unroll
    for (int r = 0; r < 4; ++r) {
      const int ku = r * 16 + fu;  // 0..63
      const float4 v = *(const float4*)(h + (size_t)(i0 + row) * F_IN + ku * 4);
      hT[ku * 4 + 0][row] = v.x; hT[ku * 4 + 1][row] = v.y;
      hT[ku * 4 + 2][row] = v.z; hT[ku * 4 + 3][row] = v.w;
    }
  }
  __syncthreads();
  const int c = t & 127;
  const int rg = t >> 7;   // 8 rows per thread
  float acc[8];
#pragma unroll
  for (int r = 0; r < 8; ++r) acc[r] = 0.f;
#pragma unroll 8
  for (int k = 0; k < F_IN; ++k) {
    const float wv = W[k * F_OUT + c];
    const float4 x0 = *(const float4*)(&hT[k][rg * 8]);      // lane-uniform -> broadcast
    const float4 x1 = *(const float4*)(&hT[k][rg * 8 + 4]);
    acc[0] = fmaf(x0.x, wv, acc[0]); acc[1] = fmaf(x0.y, wv, acc[1]);
    acc[2] = fmaf(x0.z, wv, acc[2]); acc[3] = fmaf(x0.w, wv, acc[3]);
    acc[4] = fmaf(x1.x, wv, acc[4]); acc[5] = fmaf(x1.y, wv, acc[5]);
    acc[6] = fmaf(x1.z, wv, acc[6]); acc[7] = fmaf(x1.w, wv, acc[7]);
  }
#pragma unroll
  for (int r = 0; r < 8; ++r)
    g_Wh[(size_t)(i0 + rg * 8 + r) * F_OUT + c] = acc[r];
  union { _Float16 hh[8]; uint4 u4; } pk;
#pragma unroll
  for (int r = 0; r < 8; ++r) pk.hh[r] = (_Float16)acc[r];
  *(uint4*)(g_WhT + (size_t)c * N_NODES + i0 + rg * 8) = pk.u4;
}

// ---------------- Kernel B: f1 = Wh@a1, f2 = Wh@a2 ----------------
__global__ __launch_bounds__(256) void f12_kernel(const float* __restrict__ a) {
  const int t = threadIdx.x;
  const int row = blockIdx.x * 2 + (t >> 7);
  const int c = t & 127;
  const float wh = g_Wh[(size_t)row * F_OUT + c];
  float p1 = wh * a[c];
  float p2 = wh * a[F_OUT + c];
  for (int o = 32; o > 0; o >>= 1) {
    p1 += __shfl_down(p1, o, 64);
    p2 += __shfl_down(p2, o, 64);
  }
  __shared__ float s1[4], s2[4];
  const int w = t >> 6;
  if ((t & 63) == 0) { s1[w] = p1; s2[w] = p2; }
  __syncthreads();
  if ((t & 127) == 0) {
    g_f1[row] = s1[w] + s1[w + 1];
    g_f2[row] = s2[w] + s2[w + 1];
  }
}

// ---------------- Kernel C: fused attention (partials) ----------------
__device__ __forceinline__ float score_p(int a, float f2v, float f1r) {
  float s = f1r + f2v;
  s = fmaxf(s, 0.2f * s);  // leaky_relu, alpha=0.2<1
  float arg = (a > 0) ? fmaf(s, 1.44269504088896f, -16.0f) : -1.0e5f;
  return __builtin_amdgcn_exp2f(arg);  // masked -> 0; 2^-16 scale cancels in num/den
}

__global__ __launch_bounds__(256, 4) void gat_attn_kernel(const int* __restrict__ adj) {
  const int t = threadIdx.x;
  const int wave = t >> 6;
  const int lane = t & 63;
  const int mrow = lane & 15;
  const int quad = lane >> 4;
  const int i0 = blockIdx.x * RPB;
  const int js = blockIdx.y;
  const int jbase = js * JRANGE;

  __shared__ float ldsF2[JRANGE];        // 8 KB, whole j-quarter of f2
  __shared__ float ldsO[RPB][F_OUT];     // 16 KB
  __shared__ float ldsS[4][RPB];

  // runtime C/D layout probe: D1[m][n]=m, D2[m][n]=n (self-correcting scatter)
  int rm[4], cm[4];
  {
    half8 a1f, b1f, a2f, b2f;
#pragma unroll
    for (int e = 0; e < 8; ++e) {
      a1f[e] = (_Float16)0; b1f[e] = (_Float16)0;
      a2f[e] = (_Float16)0; b2f[e] = (_Float16)0;
    }
    if (quad == 0) {
      a1f[0] = (_Float16)mrow; b1f[0] = (_Float16)1;
      a2f[0] = (_Float16)1;    b2f[0] = (_Float16)mrow;
    }
    floatx4 d1 = (floatx4)0.f, d2 = (floatx4)0.f;
    d1 = __builtin_amdgcn_mfma_f32_16x16x32_f16(a1f, b1f, d1, 0, 0, 0);
    d2 = __builtin_amdgcn_mfma_f32_16x16x32_f16(a2f, b2f, d2, 0, 0, 0);
#pragma unroll
    for (int r = 0; r < 4; ++r) { rm[r] = (int)d1[r]; cm[r] = (int)d2[r]; }
  }

  const float f1r0 = g_f1[i0 + mrow];
  const float f1r1 = g_f1[i0 + 16 + mrow];

  half8 ones;
#pragma unroll
  for (int e = 0; e < 8; ++e) ones[e] = (_Float16)1;

  floatx4 acc[2][8];
  floatx4 asum[2];
#pragma unroll
  for (int tl = 0; tl < 2; ++tl) {
    asum[tl] = (floatx4)0.f;
#pragma unroll
    for (int ct = 0; ct < 8; ++ct) acc[tl][ct] = (floatx4)0.f;
  }

  // stage the f2 quarter once (x32-row reuse justifies LDS; adj has none)
#pragma unroll
  for (int it = 0; it < 2; ++it) {
    const int u = it * 256 + t;
    *(float4*)&ldsF2[u * 4] = *(const float4*)(g_f2 + jbase + u * 4);
  }
  __syncthreads();

  const size_t rowoff0 = (size_t)(i0 + mrow) * N_NODES;
  const size_t rowoff1 = (size_t)(i0 + 16 + mrow) * N_NODES;
  const int jloc = wave * 32 + quad * 8;

  // prologue: adj for c=0 in registers
  int4 A00 = *(const int4*)(adj + rowoff0 + jbase + jloc);
  int4 A01 = *(const int4*)(adj + rowoff0 + jbase + jloc + 4);
  int4 A10 = *(const int4*)(adj + rowoff1 + jbase + jloc);
  int4 A11 = *(const int4*)(adj + rowoff1 + jbase + jloc + 4);

#pragma unroll 1
  for (int c = 0; c < NCH; ++c) {
    const int jglob = jbase + c * JCH + jloc;

    // B-frags from L2/L3 direct to VGPR. Issued FIRST: the MFMA's wait on
    // these is then vmcnt(4), leaving the adj prefetch below in flight
    // across the MFMAs and the loop back-edge.
    half8 bfr[8];
#pragma unroll
    for (int ct = 0; ct < 8; ++ct)
      bfr[ct] = *(const half8*)(g_WhT + (size_t)(ct * 16 + mrow) * N_NODES + jglob);

    // adj prefetch for iteration c+1 (depth-1 register double buffer).
    // Last iteration re-loads c=0 (clamped), values unused.
    const int jn = jbase + ((c + 1 < NCH) ? (c + 1) : 0) * JCH + jloc;
    const int4 nA00 = *(const int4*)(adj + rowoff0 + jn);
    const int4 nA01 = *(const int4*)(adj + rowoff0 + jn + 4);
    const int4 nA10 = *(const int4*)(adj + rowoff1 + jn);
    const int4 nA11 = *(const int4*)(adj + rowoff1 + jn + 4);

    const float4 F0 = *(const float4*)&ldsF2[c * JCH + jloc];
    const float4 F1 = *(const float4*)&ldsF2[c * JCH + jloc + 4];

    // scores from A (in registers since last iteration -> no memory wait)
    half8 af0, af1;
    af0[0] = (_Float16)score_p(A00.x, F0.x, f1r0);
    af0[1] = (_Float16)score_p(A00.y, F0.y, f1r0);
    af0[2] = (_Float16)score_p(A00.z, F0.z, f1r0);
    af0[3] = (_Float16)score_p(A00.w, F0.w, f1r0);
    af0[4] = (_Float16)score_p(A01.x, F1.x, f1r0);
    af0[5] = (_Float16)score_p(A01.y, F1.y, f1r0);
    af0[6] = (_Float16)score_p(A01.z, F1.z, f1r0);
    af0[7] = (_Float16)score_p(A01.w, F1.w, f1r0);
    af1[0] = (_Float16)score_p(A10.x, F0.x, f1r1);
    af1[1] = (_Float16)score_p(A10.y, F0.y, f1r1);
    af1[2] = (_Float16)score_p(A10.z, F0.z, f1r1);
    af1[3] = (_Float16)score_p(A10.w, F0.w, f1r1);
    af1[4] = (_Float16)score_p(A11.x, F1.x, f1r1);
    af1[5] = (_Float16)score_p(A11.y, F1.y, f1r1);
    af1[6] = (_Float16)score_p(A11.z, F1.z, f1r1);
    af1[7] = (_Float16)score_p(A11.w, F1.w, f1r1);

#pragma unroll
    for (int ct = 0; ct < 8; ++ct) {
      acc[0][ct] = __builtin_amdgcn_mfma_f32_16x16x32_f16(af0, bfr[ct], acc[0][ct], 0, 0, 0);
      acc[1][ct] = __builtin_amdgcn_mfma_f32_16x16x32_f16(af1, bfr[ct], acc[1][ct], 0, 0, 0);
    }
    asum[0] = __builtin_amdgcn_mfma_f32_16x16x32_f16(af0, ones, asum[0], 0, 0, 0);
    asum[1] = __builtin_amdgcn_mfma_f32_16x16x32_f16(af1, ones, asum[1], 0, 0, 0);

    // rotate prefetch registers (compiler renames, no moves)
    A00 = nA00; A01 = nA01; A10 = nA10; A11 = nA11;
    // no barrier, no waitcnt(0): waves free-run
  }

  // psum per row (all cols of asum equal; take the 4 probed rows per quad)
  if (mrow == 0) {
#pragma unroll
    for (int tl = 0; tl < 2; ++tl)
#pragma unroll
      for (int r = 0; r < 4; ++r)
        ldsS[wave][tl * 16 + rm[r]] = asum[tl][r];
  }
  // serialized wave-add of the 32x128 tile
  for (int w = 0; w < 4; ++w) {
    if (wave == w) {
#pragma unroll
      for (int tl = 0; tl < 2; ++tl)
#pragma unroll
        for (int ct = 0; ct < 8; ++ct)
#pragma unroll
          for (int r = 0; r < 4; ++r) {
            float* p = &ldsO[tl * 16 + rm[r]][ct * 16 + cm[r]];
            if (w == 0) *p = acc[tl][ct][r];
            else        *p += acc[tl][ct][r];
          }
    }
    __syncthreads();
  }
  {
    const int row = t >> 3;
    const int c0 = (t & 7) * 16;
    float* dst = g_part[js] + (size_t)(i0 + row) * F_OUT + c0;
#pragma unroll
    for (int q = 0; q < 4; ++q)
      *(f32x4*)(dst + q * 4) = *(const f32x4*)(&ldsO[row][c0 + q * 4]);
    if (t < RPB)
      g_spart[js][i0 + t] = ldsS[0][t] + ldsS[1][t] + ldsS[2][t] + ldsS[3][t];
  }
}

// ---------------- Kernel D: combine partials + normalize ----------------
__global__ __launch_bounds__(256) void comb_kernel(float* __restrict__ out) {
  const int u = blockIdx.x * 256 + threadIdx.x;  // float4 unit
  const int row = u >> 5;                        // 32 float4 per row
  const float s = g_spart[0][row] + g_spart[1][row] +
                  g_spart[2][row] + g_spart[3][row];
  const f32x4 v = ((const f32x4*)g_part[0])[u] + ((const f32x4*)g_part[1])[u] +
                  ((const f32x4*)g_part[2])[u] + ((const f32x4*)g_part[3])[u];
  ((f32x4*)out)[u] = v * (1.0f / s);
}

extern "C" void kernel_launch(void* const* d_in, const int* in_sizes, int n_in,
                              void* d_out, int out_size, void* d_ws, size_t ws_size,
                              hipStream_t stream) {
  const float* h = (const float*)d_in[0];
  const int* adj = (const int*)d_in[1];
  const float* W = (const float*)d_in[2];
  const float* a = (const float*)d_in[3];
  float* out = (float*)d_out;
  (void)d_ws; (void)ws_size;

  wh_kernel<<<dim3(N_NODES / 16), dim3(256), 0, stream>>>(h, W);
  f12_kernel<<<dim3(N_NODES / 2), dim3(256), 0, stream>>>(a);
  gat_attn_kernel<<<dim3(N_NODES / RPB, JSPLIT), dim3(256), 0, stream>>>(adj);
  comb_kernel<<<dim3(N_NODES * F_OUT / 4 / 256), dim3(256), 0, stream>>>(out);
}